// Round 23
// baseline (79.522 us; speedup 1.0000x reference)
//
#include <hip/hip_runtime.h>
#include <hip/hip_bf16.h>

#define TWO_B 4096
#define DIM_ 4096

typedef __attribute__((ext_vector_type(8))) short bf16x8;
typedef __attribute__((ext_vector_type(4))) float f32x4;
typedef __attribute__((ext_vector_type(4))) int i32x4;
typedef __attribute__((ext_vector_type(8))) int i32x8;

static __device__ __forceinline__ unsigned short f2bf(float x) {
    return __builtin_bit_cast(unsigned short, __float2bfloat16(x));
}

static __device__ __forceinline__ float waveReduceSum(float v) {
    v += __shfl_xor(v, 1);  v += __shfl_xor(v, 2);  v += __shfl_xor(v, 4);
    v += __shfl_xor(v, 8);  v += __shfl_xor(v, 16); v += __shfl_xor(v, 32);
    return v;
}
static __device__ __forceinline__ float waveReduceMax(float v) {
    v = fmaxf(v, __shfl_xor(v, 1));  v = fmaxf(v, __shfl_xor(v, 2));
    v = fmaxf(v, __shfl_xor(v, 4));  v = fmaxf(v, __shfl_xor(v, 8));
    v = fmaxf(v, __shfl_xor(v, 16)); v = fmaxf(v, __shfl_xor(v, 32));
    return v;
}

// fp4 e2m1 encode: values {0,.5,1,1.5,2,3,4,6}, round-to-nearest, sign bit 0x8.
static __device__ __forceinline__ int enc_fp4(float q) {
    float a = fabsf(q);
    int m = a < 0.25f ? 0 : a < 0.75f ? 1 : a < 1.25f ? 2 : a < 1.75f ? 3 :
            a < 2.5f  ? 4 : a < 3.5f  ? 5 : a < 5.0f  ? 6 : 7;
    return m | (q < 0.f ? 8 : 0);
}

// -------- Phase 1: per-row stats (KD, MSE, norms) + fp4 z write + quant scales.
__global__ __launch_bounds__(256) void row_stats(
    const float* __restrict__ et, const float* __restrict__ es,
    float* __restrict__ rinv, float* __restrict__ qs,
    float* __restrict__ kdp, float* __restrict__ msep,
    float* __restrict__ rowsum, char* __restrict__ z4)
{
    const int b = blockIdx.x;
    const int tid = threadIdx.x;
    const int wid = tid >> 6;

    if (b < 16) rowsum[b * 256 + tid] = 0.f;

    const float4* tp = (const float4*)(et + (size_t)b * DIM_);
    const float4* sp = (const float4*)(es + (size_t)b * DIM_);
    float4 tv[4], sv[4];
#pragma unroll
    for (int i = 0; i < 4; ++i) { tv[i] = tp[tid * 4 + i]; sv[i] = sp[tid * 4 + i]; }

    float mt = -1e30f, ms = -1e30f, amt = 0.f, ams = 0.f;
    float nt2 = 0.f, ns2 = 0.f, msev = 0.f;
#pragma unroll
    for (int i = 0; i < 4; ++i) {
        const float* tx = (const float*)&tv[i];
        const float* sx = (const float*)&sv[i];
#pragma unroll
        for (int j = 0; j < 4; ++j) {
            float a = tx[j], c = sx[j];
            mt = fmaxf(mt, a); ms = fmaxf(ms, c);
            amt = fmaxf(amt, fabsf(a)); ams = fmaxf(ams, fabsf(c));
            nt2 += a * a; ns2 += c * c;
            float d = c - a; msev += d * d;
        }
    }
    mt = waveReduceMax(mt); ms = waveReduceMax(ms);
    amt = waveReduceMax(amt); ams = waveReduceMax(ams);
    __shared__ float smx[4], sms[4], sat[4], sas[4];
    if ((tid & 63) == 0) { smx[wid] = mt; sms[wid] = ms; sat[wid] = amt; sas[wid] = ams; }
    __syncthreads();
    mt = fmaxf(fmaxf(smx[0], smx[1]), fmaxf(smx[2], smx[3]));
    ms = fmaxf(fmaxf(sms[0], sms[1]), fmaxf(sms[2], sms[3]));
    const float maT = fmaxf(fmaxf(fmaxf(sat[0], sat[1]), fmaxf(sat[2], sat[3])), 1e-20f);
    const float maS = fmaxf(fmaxf(fmaxf(sas[0], sas[1]), fmaxf(sas[2], sas[3])), 1e-20f);

    float se_t = 0.f, st = 0.f, sx_ = 0.f, se_s = 0.f;
#pragma unroll
    for (int i = 0; i < 4; ++i) {
        const float* tx = (const float*)&tv[i];
        const float* sx = (const float*)&sv[i];
#pragma unroll
        for (int j = 0; j < 4; ++j) {
            float a = tx[j], c = sx[j];
            float e = __expf(a - mt);
            se_t += e; st += e * a; sx_ += e * c;
            se_s += __expf(c - ms);
        }
    }
    float v0 = waveReduceSum(se_t), v1 = waveReduceSum(st), v2 = waveReduceSum(sx_);
    float v3 = waveReduceSum(se_s), v4 = waveReduceSum(nt2), v5 = waveReduceSum(ns2);
    float v6 = waveReduceSum(msev);
    __shared__ float sred[7][4];
    if ((tid & 63) == 0) {
        sred[0][wid] = v0; sred[1][wid] = v1; sred[2][wid] = v2; sred[3][wid] = v3;
        sred[4][wid] = v4; sred[5][wid] = v5; sred[6][wid] = v6;
    }
    __syncthreads();
    const float rT = sred[4][0] + sred[4][1] + sred[4][2] + sred[4][3];
    const float rS = sred[5][0] + sred[5][1] + sred[5][2] + sred[5][3];
    const float rinvT = 1.f / fmaxf(sqrtf(rT), 1e-8f);
    const float rinvS = 1.f / fmaxf(sqrtf(rS), 1e-8f);

    if (tid == 0) {
        float r0 = sred[0][0] + sred[0][1] + sred[0][2] + sred[0][3];
        float r1 = sred[1][0] + sred[1][1] + sred[1][2] + sred[1][3];
        float r2 = sred[2][0] + sred[2][1] + sred[2][2] + sred[2][3];
        float r3 = sred[3][0] + sred[3][1] + sred[3][2] + sred[3][3];
        float r6 = sred[6][0] + sred[6][1] + sred[6][2] + sred[6][3];
        float lse_t = mt + logf(r0);
        float lse_s = ms + logf(r3);
        kdp[b]  = (r1 - r2) / r0 - lse_t + lse_s;
        msep[b] = r6;
        rinv[b]        = rinvT;
        rinv[b + 2048] = rinvS;
        qs[b]          = maT * rinvT * (1.f / 6.f);
        qs[b + 2048]   = maS * rinvS * (1.f / 6.f);
    }

    if (z4) {
        const float gT = 6.f / maT, gS = 6.f / maS;
        int wt[2] = {0, 0}, wsv[2] = {0, 0};
#pragma unroll
        for (int i = 0; i < 4; ++i) {
            const float* tx = (const float*)&tv[i];
            const float* sx = (const float*)&sv[i];
            int bt = (enc_fp4(tx[0] * gT)) | (enc_fp4(tx[1] * gT) << 4) |
                     (enc_fp4(tx[2] * gT) << 8) | (enc_fp4(tx[3] * gT) << 12);
            int bs = (enc_fp4(sx[0] * gS)) | (enc_fp4(sx[1] * gS) << 4) |
                     (enc_fp4(sx[2] * gS) << 8) | (enc_fp4(sx[3] * gS) << 12);
            wt[i >> 1] |= bt << (16 * (i & 1));
            wsv[i >> 1] |= bs << (16 * (i & 1));
        }
        ((int2*)(z4 + (size_t)b * 2048))[tid] = make_int2(wt[0], wt[1]);
        ((int2*)(z4 + (size_t)(b + 2048) * 2048))[tid] = make_int2(wsv[0], wsv[1]);
    }
}

// -------- Phase 2: fp4 GEMM, double-buffered with COUNTED vmcnt (T3+T4).
// z is 8MB -> L2-resident: stage latency ~300cy, coverable by the prefetch.
// 64KB LDS = 2 blocks/CU capacity = the realized occupancy at 32KB (528 grid
// = 2.06/CU), so unlike r7 there is NO occupancy cost. Pattern per tile:
// wait own vmcnt(N) -> raw barrier -> COMPUTE -> raw barrier -> STAGE(t+2).
// N = loads of one tile still outstanding (8 off-diag, 4 diag); never 0
// until the final tile. Geometry identical to the verified r22 fp4 kernel.
__global__ __launch_bounds__(256, 2) void cont_gemm_fp4db(
    const char* __restrict__ z4, const float* __restrict__ qs,
    float* __restrict__ rowsum, float* __restrict__ pos)
{
    const int bid = blockIdx.x;
    int t = (bid & 7) * 66 + (bid >> 3);
    int bi = 0;
    while (t >= (32 - bi)) { t -= (32 - bi); ++bi; }
    const int bj = bi + t;
    const int brow = bi * 128, bcol = bj * 128;
    const bool dg = (bi == bj);

    __shared__ char As[2][128 * 128];  // 32 KB
    __shared__ char Bs[2][128 * 128];  // 32 KB

    const int tid = threadIdx.x;
    const int lane = tid & 63;
    const int wid = tid >> 6;
    const int wm = wid >> 1, wn = wid & 1;
    const int lrow = lane >> 3;
    const int lblk = lane & 7;

    const char* srcA[4];
    const char* srcB[4];
#pragma unroll
    for (int i = 0; i < 4; ++i) {
        int r = wid * 32 + i * 8 + lrow;
        srcA[i] = z4 + (size_t)(brow + r) * 2048 + ((lblk ^ lrow) << 4);
        srcB[i] = z4 + (size_t)(bcol + r) * 2048 + ((lblk ^ lrow) << 4);
    }

    const int sc1 = 0x7F7F7F7F;   // e8m0 127 = 1.0 in every byte

    f32x4 acc[4][4] = {};

    auto STAGE = [&](int buf, int step) {
        const int ktb = step * 128;
#pragma unroll
        for (int i = 0; i < 4; ++i) {
            char* dstA = &As[buf][(wid * 32 + i * 8) * 128];
            __builtin_amdgcn_global_load_lds(
                (const __attribute__((address_space(1))) unsigned int*)(srcA[i] + ktb),
                (__attribute__((address_space(3))) unsigned int*)dstA, 16, 0, 0);
        }
        if (!dg) {
#pragma unroll
            for (int i = 0; i < 4; ++i) {
                char* dstB = &Bs[buf][(wid * 32 + i * 8) * 128];
                __builtin_amdgcn_global_load_lds(
                    (const __attribute__((address_space(1))) unsigned int*)(srcB[i] + ktb),
                    (__attribute__((address_space(3))) unsigned int*)dstB, 16, 0, 0);
            }
        }
    };

    auto COMPUTE = [&](int buf) {
        const char* Ab = &As[buf][0];
        const char* Bb = dg ? &As[buf][0] : &Bs[buf][0];
        const int li = lane & 15;
#pragma unroll
        for (int ks = 0; ks < 2; ++ks) {
            i32x4 af4[4], bf4[4];
            const int kb = ks * 64 + (lane >> 4) * 16;
#pragma unroll
            for (int m = 0; m < 4; ++m) {
                int r = wm * 64 + m * 16 + li;
                int off = (r * 128 + kb) ^ ((r & 7) << 4);
                af4[m] = *(const i32x4*)(Ab + off);
            }
#pragma unroll
            for (int n = 0; n < 4; ++n) {
                int r = wn * 64 + n * 16 + li;
                int off = (r * 128 + kb) ^ ((r & 7) << 4);
                bf4[n] = *(const i32x4*)(Bb + off);
            }
            __builtin_amdgcn_s_setprio(1);
#pragma unroll
            for (int m = 0; m < 4; ++m) {
                i32x8 a8 = {af4[m][0], af4[m][1], af4[m][2], af4[m][3], 0, 0, 0, 0};
#pragma unroll
                for (int n = 0; n < 4; ++n) {
                    i32x8 b8 = {bf4[n][0], bf4[n][1], bf4[n][2], bf4[n][3], 0, 0, 0, 0};
                    acc[m][n] = __builtin_amdgcn_mfma_scale_f32_16x16x128_f8f6f4(
                        a8, b8, acc[m][n], 4, 4, 0, sc1, 0, sc1);
                }
            }
            __builtin_amdgcn_s_setprio(0);
        }
    };

    auto WAIT_TILE = [&](bool last) {
        if (last) {
            asm volatile("s_waitcnt vmcnt(0)" ::: "memory");
        } else if (dg) {
            asm volatile("s_waitcnt vmcnt(4)" ::: "memory");
        } else {
            asm volatile("s_waitcnt vmcnt(8)" ::: "memory");
        }
    };

    // Prologue: tiles 0 and 1 in flight.
    STAGE(0, 0);
    STAGE(1, 1);

    // 16 tiles total, manual 2x unroll for static buffer indices.
    for (int tt = 0; tt < 14; tt += 2) {
        WAIT_TILE(false);
        __builtin_amdgcn_s_barrier();
        COMPUTE(0);
        __builtin_amdgcn_s_barrier();
        STAGE(0, tt + 2);
        WAIT_TILE(false);
        __builtin_amdgcn_s_barrier();
        COMPUTE(1);
        __builtin_amdgcn_s_barrier();
        STAGE(1, tt + 3);
    }
    // Epilogue pair: tiles 14 and 15 (no more stages).
    WAIT_TILE(false);
    __builtin_amdgcn_s_barrier();
    COMPUTE(0);
    __builtin_amdgcn_s_barrier();
    WAIT_TILE(true);
    __builtin_amdgcn_s_barrier();
    COMPUTE(1);

    // -------- epilogue: dequant, exp, diagonal mask, positives, row/col sums
    const bool posT = (bj == bi + 16);
    const int li = lane & 15;
    const int lg = lane >> 4;
    float sB[4];
#pragma unroll
    for (int n = 0; n < 4; ++n) sB[n] = qs[bcol + wn * 64 + n * 16 + li];
    float cs[4] = {0.f, 0.f, 0.f, 0.f};
#pragma unroll
    for (int m = 0; m < 4; ++m) {
#pragma unroll
        for (int q = 0; q < 4; ++q) {
            int lr = wm * 64 + m * 16 + lg * 4 + q;
            int gr = brow + lr;
            float sA = qs[gr];
            float rsum = 0.f;
#pragma unroll
            for (int n = 0; n < 4; ++n) {
                int gc = bcol + wn * 64 + n * 16 + li;
                float v = acc[m][n][q] * sA * sB[n];
                if (posT && gc == gr + 2048) { pos[gr] = v; pos[gc] = v; }
                float e = (dg && gr == gc) ? 0.f : __expf(2.0f * v);
                rsum += e;
                cs[n] += e;
            }
            rsum += __shfl_xor(rsum, 1);
            rsum += __shfl_xor(rsum, 2);
            rsum += __shfl_xor(rsum, 4);
            rsum += __shfl_xor(rsum, 8);
            if (li == 0) atomicAdd(&rowsum[gr], rsum);
        }
    }
    if (!dg) {
#pragma unroll
        for (int n = 0; n < 4; ++n) {
            float v = cs[n];
            v += __shfl_xor(v, 16);
            v += __shfl_xor(v, 32);
            if (lg == 0) atomicAdd(&rowsum[bcol + wn * 64 + n * 16 + li], v);
        }
    }
}

// -------- Fallback (no-ws path): on-the-fly normalize 128x128 bf16.
__global__ __launch_bounds__(256) void cont_gemm(
    const float* __restrict__ et, const float* __restrict__ es,
    const float* __restrict__ rinv, float* __restrict__ rowsum,
    float* __restrict__ pos)
{
    int t = blockIdx.x;
    int bi = 0;
    while (t >= (32 - bi)) { t -= (32 - bi); ++bi; }
    const int bj = bi + t;
    const int brow = bi * 128, bcol = bj * 128;

    __shared__ unsigned short As[128 * 64];
    __shared__ unsigned short Bs[128 * 64];

    const int tid = threadIdx.x;
    const int lane = tid & 63;
    const int wid = tid >> 6;
    const int wm = wid >> 1, wn = wid & 1;

    const int srow = tid >> 4;
    const int sf4 = tid & 15;

    const float* pA[8]; const float* pB[8];
    float riA[8], riB[8];
#pragma unroll
    for (int it = 0; it < 8; ++it) {
        int r = srow + it * 16;
        int ga = brow + r;
        int gb = bcol + r;
        pA[it] = (ga < 2048) ? (et + (size_t)ga * DIM_) : (es + (size_t)(ga - 2048) * DIM_);
        pB[it] = (gb < 2048) ? (et + (size_t)gb * DIM_) : (es + (size_t)(gb - 2048) * DIM_);
        riA[it] = rinv[ga]; riB[it] = rinv[gb];
    }

    f32x4 acc[4][4] = {};

    for (int kt = 0; kt < DIM_; kt += 64) {
        __syncthreads();
#pragma unroll
        for (int it = 0; it < 8; ++it) {
            int r = srow + it * 16;
            int swz = (r & 7) << 4;
            int bo = (r * 128 + sf4 * 8) ^ swz;
            {
                float4 v = *(const float4*)(pA[it] + kt + sf4 * 4);
                float ri = riA[it];
                ushort4 pk = make_ushort4(f2bf(v.x * ri), f2bf(v.y * ri),
                                          f2bf(v.z * ri), f2bf(v.w * ri));
                *(ushort4*)((char*)As + bo) = pk;
            }
            {
                float4 v = *(const float4*)(pB[it] + kt + sf4 * 4);
                float ri = riB[it];
                ushort4 pk = make_ushort4(f2bf(v.x * ri), f2bf(v.y * ri),
                                          f2bf(v.z * ri), f2bf(v.w * ri));
                *(ushort4*)((char*)Bs + bo) = pk;
            }
        }
        __syncthreads();
#pragma unroll
        for (int ks = 0; ks < 2; ++ks) {
            bf16x8 af[4], bfr[4];
            const int li = lane & 15;
            const int kb = ks * 64 + (lane >> 4) * 16;
#pragma unroll
            for (int m = 0; m < 4; ++m) {
                int r = wm * 64 + m * 16 + li;
                int off = (r * 128 + kb) ^ ((r & 7) << 4);
                af[m] = *(const bf16x8*)((const char*)As + off);
            }
#pragma unroll
            for (int n = 0; n < 4; ++n) {
                int r = wn * 64 + n * 16 + li;
                int off = (r * 128 + kb) ^ ((r & 7) << 4);
                bfr[n] = *(const bf16x8*)((const char*)Bs + off);
            }
#pragma unroll
            for (int m = 0; m < 4; ++m)
#pragma unroll
                for (int n = 0; n < 4; ++n)
                    acc[m][n] = __builtin_amdgcn_mfma_f32_16x16x32_bf16(
                        af[m], bfr[n], acc[m][n], 0, 0, 0);
        }
    }

    const bool diag = (bi == bj);
    const bool posT = (bcol == (brow ^ 2048));
    const int li = lane & 15;
    const int lg = lane >> 4;
    float cs[4] = {0.f, 0.f, 0.f, 0.f};
#pragma unroll
    for (int m = 0; m < 4; ++m) {
#pragma unroll
        for (int q = 0; q < 4; ++q) {
            int lr = wm * 64 + m * 16 + lg * 4 + q;
            float rsum = 0.f;
#pragma unroll
            for (int n = 0; n < 4; ++n) {
                int lc = wn * 64 + n * 16 + li;
                float v = acc[m][n][q];
                if (posT && lc == lr) { pos[brow + lr] = v; pos[bcol + lc] = v; }
                float e = (diag && lc == lr) ? 0.f : __expf(2.0f * v);
                rsum += e;
                cs[n] += e;
            }
            rsum += __shfl_xor(rsum, 1);
            rsum += __shfl_xor(rsum, 2);
            rsum += __shfl_xor(rsum, 4);
            rsum += __shfl_xor(rsum, 8);
            if (li == 0) atomicAdd(&rowsum[brow + lr], rsum);
        }
    }
    if (!diag) {
#pragma unroll
        for (int n = 0; n < 4; ++n) {
            float v = cs[n];
            v += __shfl_xor(v, 16);
            v += __shfl_xor(v, 32);
            if (lg == 0) atomicAdd(&rowsum[bcol + wn * 64 + n * 16 + li], v);
        }
    }
}

// -------- Phase 3: finalize scalar loss (also reduces kd/mse partials)
__global__ __launch_bounds__(256) void finalize(
    const float* __restrict__ rowsum, const float* __restrict__ pos,
    const float* __restrict__ kdp, const float* __restrict__ msep,
    float* __restrict__ out)
{
    const int tid = threadIdx.x;
    float c = 0.f;
    for (int i = tid; i < TWO_B; i += 256)
        c += logf(rowsum[i]) - 2.0f * pos[i];
    float kd = 0.f, ms = 0.f;
    for (int i = tid; i < 2048; i += 256) { kd += kdp[i]; ms += msep[i]; }
    c = waveReduceSum(c); kd = waveReduceSum(kd); ms = waveReduceSum(ms);
    __shared__ float sm[3][4];
    if ((tid & 63) == 0) { sm[0][tid >> 6] = c; sm[1][tid >> 6] = kd; sm[2][tid >> 6] = ms; }
    __syncthreads();
    if (tid == 0) {
        float cont = (sm[0][0] + sm[0][1] + sm[0][2] + sm[0][3]) / 4096.0f;
        float kds  = (sm[1][0] + sm[1][1] + sm[1][2] + sm[1][3]) / 2048.0f;
        float mses = (sm[2][0] + sm[2][1] + sm[2][2] + sm[2][3]) / (2048.0f * 4096.0f);
        out[0] = cont + kds + mses;
    }
}

extern "C" void kernel_launch(void* const* d_in, const int* in_sizes, int n_in,
                              void* d_out, int out_size, void* d_ws, size_t ws_size,
                              hipStream_t stream) {
    const float* et = (const float*)d_in[0];
    const float* es = (const float*)d_in[1];

    const size_t Z_BYTES = (size_t)TWO_B * 2048;  // 8 MiB fp4
    const size_t SMALL_FLOATS = 4096 * 4 + 2048 * 2;
    const bool fast = ws_size >= Z_BYTES + SMALL_FLOATS * sizeof(float);

    if (fast) {
        char* z4 = (char*)d_ws;
        float* smallf = (float*)((char*)d_ws + Z_BYTES);
        float* rowsum = smallf;
        float* pos  = smallf + 4096;
        float* qs   = smallf + 4096 * 2;
        float* rinv = smallf + 4096 * 3;
        float* kdp  = smallf + 4096 * 4;
        float* msep = smallf + 4096 * 4 + 2048;
        hipLaunchKernelGGL(row_stats, dim3(2048), dim3(256), 0, stream,
                           et, es, rinv, qs, kdp, msep, rowsum, z4);
        hipLaunchKernelGGL(cont_gemm_fp4db, dim3(528), dim3(256), 0, stream, z4, qs, rowsum, pos);
        hipLaunchKernelGGL(finalize, dim3(1), dim3(256), 0, stream, rowsum, pos, kdp, msep, (float*)d_out);
    } else {
        float* ws = (float*)d_ws;
        float* rowsum = ws;
        float* pos  = ws + 4096;
        float* qs   = ws + 4096 * 2;
        float* rinv = ws + 4096 * 3;
        float* kdp  = ws + 4096 * 4;
        float* msep = ws + 4096 * 4 + 2048;
        hipMemsetAsync(rowsum, 0, 4096 * sizeof(float), stream);
        hipLaunchKernelGGL(row_stats, dim3(2048), dim3(256), 0, stream,
                           et, es, rinv, qs, kdp, msep, rowsum, (char*)nullptr);
        hipLaunchKernelGGL(cont_gemm, dim3(528), dim3(256), 0, stream, et, es, rinv, rowsum, pos);
        hipLaunchKernelGGL(finalize, dim3(1), dim3(256), 0, stream, rowsum, pos, kdp, msep, (float*)d_out);
    }
}

// Round 24
// 65.269 us; speedup vs baseline: 1.2184x; 1.2184x over previous
//
#include <hip/hip_runtime.h>
#include <hip/hip_bf16.h>

#define TWO_B 4096
#define DIM_ 4096

typedef __attribute__((ext_vector_type(8))) short bf16x8;
typedef __attribute__((ext_vector_type(4))) float f32x4;
typedef __attribute__((ext_vector_type(4))) int i32x4;
typedef __attribute__((ext_vector_type(8))) int i32x8;

static __device__ __forceinline__ unsigned short f2bf(float x) {
    return __builtin_bit_cast(unsigned short, __float2bfloat16(x));
}

static __device__ __forceinline__ float waveReduceSum(float v) {
    v += __shfl_xor(v, 1);  v += __shfl_xor(v, 2);  v += __shfl_xor(v, 4);
    v += __shfl_xor(v, 8);  v += __shfl_xor(v, 16); v += __shfl_xor(v, 32);
    return v;
}
static __device__ __forceinline__ float waveReduceMax(float v) {
    v = fmaxf(v, __shfl_xor(v, 1));  v = fmaxf(v, __shfl_xor(v, 2));
    v = fmaxf(v, __shfl_xor(v, 4));  v = fmaxf(v, __shfl_xor(v, 8));
    v = fmaxf(v, __shfl_xor(v, 16)); v = fmaxf(v, __shfl_xor(v, 32));
    return v;
}

// fp4 e2m1 encode: values {0,.5,1,1.5,2,3,4,6}, round-to-nearest, sign bit 0x8.
static __device__ __forceinline__ int enc_fp4(float q) {
    float a = fabsf(q);
    int m = a < 0.25f ? 0 : a < 0.75f ? 1 : a < 1.25f ? 2 : a < 1.75f ? 3 :
            a < 2.5f  ? 4 : a < 3.5f  ? 5 : a < 5.0f  ? 6 : 7;
    return m | (q < 0.f ? 8 : 0);
}

// -------- Phase 1: per-row stats (KD, MSE, norms) + fp4 z write + quant scales.
__global__ __launch_bounds__(256) void row_stats(
    const float* __restrict__ et, const float* __restrict__ es,
    float* __restrict__ rinv, float* __restrict__ qs,
    float* __restrict__ kdp, float* __restrict__ msep,
    float* __restrict__ rowsum, char* __restrict__ z4)
{
    const int b = blockIdx.x;
    const int tid = threadIdx.x;
    const int wid = tid >> 6;

    if (b < 16) rowsum[b * 256 + tid] = 0.f;

    const float4* tp = (const float4*)(et + (size_t)b * DIM_);
    const float4* sp = (const float4*)(es + (size_t)b * DIM_);
    float4 tv[4], sv[4];
#pragma unroll
    for (int i = 0; i < 4; ++i) { tv[i] = tp[tid * 4 + i]; sv[i] = sp[tid * 4 + i]; }

    float mt = -1e30f, ms = -1e30f, amt = 0.f, ams = 0.f;
    float nt2 = 0.f, ns2 = 0.f, msev = 0.f;
#pragma unroll
    for (int i = 0; i < 4; ++i) {
        const float* tx = (const float*)&tv[i];
        const float* sx = (const float*)&sv[i];
#pragma unroll
        for (int j = 0; j < 4; ++j) {
            float a = tx[j], c = sx[j];
            mt = fmaxf(mt, a); ms = fmaxf(ms, c);
            amt = fmaxf(amt, fabsf(a)); ams = fmaxf(ams, fabsf(c));
            nt2 += a * a; ns2 += c * c;
            float d = c - a; msev += d * d;
        }
    }
    mt = waveReduceMax(mt); ms = waveReduceMax(ms);
    amt = waveReduceMax(amt); ams = waveReduceMax(ams);
    __shared__ float smx[4], sms[4], sat[4], sas[4];
    if ((tid & 63) == 0) { smx[wid] = mt; sms[wid] = ms; sat[wid] = amt; sas[wid] = ams; }
    __syncthreads();
    mt = fmaxf(fmaxf(smx[0], smx[1]), fmaxf(smx[2], smx[3]));
    ms = fmaxf(fmaxf(sms[0], sms[1]), fmaxf(sms[2], sms[3]));
    const float maT = fmaxf(fmaxf(fmaxf(sat[0], sat[1]), fmaxf(sat[2], sat[3])), 1e-20f);
    const float maS = fmaxf(fmaxf(fmaxf(sas[0], sas[1]), fmaxf(sas[2], sas[3])), 1e-20f);

    float se_t = 0.f, st = 0.f, sx_ = 0.f, se_s = 0.f;
#pragma unroll
    for (int i = 0; i < 4; ++i) {
        const float* tx = (const float*)&tv[i];
        const float* sx = (const float*)&sv[i];
#pragma unroll
        for (int j = 0; j < 4; ++j) {
            float a = tx[j], c = sx[j];
            float e = __expf(a - mt);
            se_t += e; st += e * a; sx_ += e * c;
            se_s += __expf(c - ms);
        }
    }
    float v0 = waveReduceSum(se_t), v1 = waveReduceSum(st), v2 = waveReduceSum(sx_);
    float v3 = waveReduceSum(se_s), v4 = waveReduceSum(nt2), v5 = waveReduceSum(ns2);
    float v6 = waveReduceSum(msev);
    __shared__ float sred[7][4];
    if ((tid & 63) == 0) {
        sred[0][wid] = v0; sred[1][wid] = v1; sred[2][wid] = v2; sred[3][wid] = v3;
        sred[4][wid] = v4; sred[5][wid] = v5; sred[6][wid] = v6;
    }
    __syncthreads();
    const float rT = sred[4][0] + sred[4][1] + sred[4][2] + sred[4][3];
    const float rS = sred[5][0] + sred[5][1] + sred[5][2] + sred[5][3];
    const float rinvT = 1.f / fmaxf(sqrtf(rT), 1e-8f);
    const float rinvS = 1.f / fmaxf(sqrtf(rS), 1e-8f);

    if (tid == 0) {
        float r0 = sred[0][0] + sred[0][1] + sred[0][2] + sred[0][3];
        float r1 = sred[1][0] + sred[1][1] + sred[1][2] + sred[1][3];
        float r2 = sred[2][0] + sred[2][1] + sred[2][2] + sred[2][3];
        float r3 = sred[3][0] + sred[3][1] + sred[3][2] + sred[3][3];
        float r6 = sred[6][0] + sred[6][1] + sred[6][2] + sred[6][3];
        float lse_t = mt + logf(r0);
        float lse_s = ms + logf(r3);
        kdp[b]  = (r1 - r2) / r0 - lse_t + lse_s;
        msep[b] = r6;
        rinv[b]        = rinvT;
        rinv[b + 2048] = rinvS;
        qs[b]          = maT * rinvT * (1.f / 6.f);
        qs[b + 2048]   = maS * rinvS * (1.f / 6.f);
    }

    if (z4) {
        const float gT = 6.f / maT, gS = 6.f / maS;
        int wt[2] = {0, 0}, wsv[2] = {0, 0};
#pragma unroll
        for (int i = 0; i < 4; ++i) {
            const float* tx = (const float*)&tv[i];
            const float* sx = (const float*)&sv[i];
            int bt = (enc_fp4(tx[0] * gT)) | (enc_fp4(tx[1] * gT) << 4) |
                     (enc_fp4(tx[2] * gT) << 8) | (enc_fp4(tx[3] * gT) << 12);
            int bs = (enc_fp4(sx[0] * gS)) | (enc_fp4(sx[1] * gS) << 4) |
                     (enc_fp4(sx[2] * gS) << 8) | (enc_fp4(sx[3] * gS) << 12);
            wt[i >> 1] |= bt << (16 * (i & 1));
            wsv[i >> 1] |= bs << (16 * (i & 1));
        }
        ((int2*)(z4 + (size_t)b * 2048))[tid] = make_int2(wt[0], wt[1]);
        ((int2*)(z4 + (size_t)(b + 2048) * 2048))[tid] = make_int2(wsv[0], wsv[1]);
    }
}

// -------- Phase 2 (r22, best measured: total 66.5us): fp4 GEMM, unit MX
// scales, r11 structure: 528 upper-tri 128x128 tiles (8*66 XCD-swizzle),
// 4 waves of 64x64, single 32KB LDS, 2-barrier sync, diag dedup,
// XOR-swizzle rule 21. 16 K-steps of BK=256 fp4 elements (128B/row).
// Counted-vmcnt dbuf variant (r23) regressed (47us, VGPR 128): confirmed
// the single-buffer loop + cross-block overlap is this family's optimum.
__global__ __launch_bounds__(256, 2) void cont_gemm_fp4(
    const char* __restrict__ z4, const float* __restrict__ qs,
    float* __restrict__ rowsum, float* __restrict__ pos)
{
    const int bid = blockIdx.x;
    int t = (bid & 7) * 66 + (bid >> 3);
    int bi = 0;
    while (t >= (32 - bi)) { t -= (32 - bi); ++bi; }
    const int bj = bi + t;
    const int brow = bi * 128, bcol = bj * 128;
    const bool dg = (bi == bj);

    __shared__ char As[128 * 128];  // 16 KB: 128 rows x 128B (256 fp4)
    __shared__ char Bs[128 * 128];  // 16 KB

    const int tid = threadIdx.x;
    const int lane = tid & 63;
    const int wid = tid >> 6;
    const int wm = wid >> 1, wn = wid & 1;
    const int lrow = lane >> 3;
    const int lblk = lane & 7;

    const char* srcA[4];
    const char* srcB[4];
#pragma unroll
    for (int i = 0; i < 4; ++i) {
        int r = wid * 32 + i * 8 + lrow;
        srcA[i] = z4 + (size_t)(brow + r) * 2048 + ((lblk ^ lrow) << 4);
        srcB[i] = z4 + (size_t)(bcol + r) * 2048 + ((lblk ^ lrow) << 4);
    }

    const char* Bbase = dg ? As : Bs;
    const int sc1 = 0x7F7F7F7F;   // e8m0 127 = 2^0 in every byte -> scale 1.0

    f32x4 acc[4][4] = {};

    for (int ktb = 0; ktb < 2048; ktb += 128) {   // 16 steps, 128B of each row
        __syncthreads();
#pragma unroll
        for (int i = 0; i < 4; ++i) {
            char* dstA = As + (wid * 32 + i * 8) * 128;
            __builtin_amdgcn_global_load_lds(
                (const __attribute__((address_space(1))) unsigned int*)(srcA[i] + ktb),
                (__attribute__((address_space(3))) unsigned int*)dstA, 16, 0, 0);
        }
        if (!dg) {
#pragma unroll
            for (int i = 0; i < 4; ++i) {
                char* dstB = Bs + (wid * 32 + i * 8) * 128;
                __builtin_amdgcn_global_load_lds(
                    (const __attribute__((address_space(1))) unsigned int*)(srcB[i] + ktb),
                    (__attribute__((address_space(3))) unsigned int*)dstB, 16, 0, 0);
            }
        }
        __syncthreads();
#pragma unroll
        for (int ks = 0; ks < 2; ++ks) {
            i32x4 af4[4], bf4[4];
            const int li = lane & 15;
            const int kb = ks * 64 + (lane >> 4) * 16;   // 16B = 32 fp4 k-elems
#pragma unroll
            for (int m = 0; m < 4; ++m) {
                int r = wm * 64 + m * 16 + li;
                int off = (r * 128 + kb) ^ ((r & 7) << 4);
                af4[m] = *(const i32x4*)(As + off);
            }
#pragma unroll
            for (int n = 0; n < 4; ++n) {
                int r = wn * 64 + n * 16 + li;
                int off = (r * 128 + kb) ^ ((r & 7) << 4);
                bf4[n] = *(const i32x4*)(Bbase + off);
            }
            __builtin_amdgcn_s_setprio(1);
#pragma unroll
            for (int m = 0; m < 4; ++m) {
                i32x8 a8 = {af4[m][0], af4[m][1], af4[m][2], af4[m][3], 0, 0, 0, 0};
#pragma unroll
                for (int n = 0; n < 4; ++n) {
                    i32x8 b8 = {bf4[n][0], bf4[n][1], bf4[n][2], bf4[n][3], 0, 0, 0, 0};
                    acc[m][n] = __builtin_amdgcn_mfma_scale_f32_16x16x128_f8f6f4(
                        a8, b8, acc[m][n], 4, 4, 0, sc1, 0, sc1);
                }
            }
            __builtin_amdgcn_s_setprio(0);
        }
    }

    // -------- epilogue: dequant, exp, diagonal mask, positives, row/col sums
    const bool posT = (bj == bi + 16);
    const int li = lane & 15;
    const int lg = lane >> 4;
    float sB[4];
#pragma unroll
    for (int n = 0; n < 4; ++n) sB[n] = qs[bcol + wn * 64 + n * 16 + li];
    float cs[4] = {0.f, 0.f, 0.f, 0.f};
#pragma unroll
    for (int m = 0; m < 4; ++m) {
#pragma unroll
        for (int q = 0; q < 4; ++q) {
            int lr = wm * 64 + m * 16 + lg * 4 + q;
            int gr = brow + lr;
            float sA = qs[gr];
            float rsum = 0.f;
#pragma unroll
            for (int n = 0; n < 4; ++n) {
                int gc = bcol + wn * 64 + n * 16 + li;
                float v = acc[m][n][q] * sA * sB[n];
                if (posT && gc == gr + 2048) { pos[gr] = v; pos[gc] = v; }
                float e = (dg && gr == gc) ? 0.f : __expf(2.0f * v);
                rsum += e;
                cs[n] += e;
            }
            rsum += __shfl_xor(rsum, 1);
            rsum += __shfl_xor(rsum, 2);
            rsum += __shfl_xor(rsum, 4);
            rsum += __shfl_xor(rsum, 8);
            if (li == 0) atomicAdd(&rowsum[gr], rsum);
        }
    }
    if (!dg) {
#pragma unroll
        for (int n = 0; n < 4; ++n) {
            float v = cs[n];
            v += __shfl_xor(v, 16);
            v += __shfl_xor(v, 32);
            if (lg == 0) atomicAdd(&rowsum[bcol + wn * 64 + n * 16 + li], v);
        }
    }
}

// -------- Fallback (no-ws path): on-the-fly normalize 128x128 bf16.
__global__ __launch_bounds__(256) void cont_gemm(
    const float* __restrict__ et, const float* __restrict__ es,
    const float* __restrict__ rinv, float* __restrict__ rowsum,
    float* __restrict__ pos)
{
    int t = blockIdx.x;
    int bi = 0;
    while (t >= (32 - bi)) { t -= (32 - bi); ++bi; }
    const int bj = bi + t;
    const int brow = bi * 128, bcol = bj * 128;

    __shared__ unsigned short As[128 * 64];
    __shared__ unsigned short Bs[128 * 64];

    const int tid = threadIdx.x;
    const int lane = tid & 63;
    const int wid = tid >> 6;
    const int wm = wid >> 1, wn = wid & 1;

    const int srow = tid >> 4;
    const int sf4 = tid & 15;

    const float* pA[8]; const float* pB[8];
    float riA[8], riB[8];
#pragma unroll
    for (int it = 0; it < 8; ++it) {
        int r = srow + it * 16;
        int ga = brow + r;
        int gb = bcol + r;
        pA[it] = (ga < 2048) ? (et + (size_t)ga * DIM_) : (es + (size_t)(ga - 2048) * DIM_);
        pB[it] = (gb < 2048) ? (et + (size_t)gb * DIM_) : (es + (size_t)(gb - 2048) * DIM_);
        riA[it] = rinv[ga]; riB[it] = rinv[gb];
    }

    f32x4 acc[4][4] = {};

    for (int kt = 0; kt < DIM_; kt += 64) {
        __syncthreads();
#pragma unroll
        for (int it = 0; it < 8; ++it) {
            int r = srow + it * 16;
            int swz = (r & 7) << 4;
            int bo = (r * 128 + sf4 * 8) ^ swz;
            {
                float4 v = *(const float4*)(pA[it] + kt + sf4 * 4);
                float ri = riA[it];
                ushort4 pk = make_ushort4(f2bf(v.x * ri), f2bf(v.y * ri),
                                          f2bf(v.z * ri), f2bf(v.w * ri));
                *(ushort4*)((char*)As + bo) = pk;
            }
            {
                float4 v = *(const float4*)(pB[it] + kt + sf4 * 4);
                float ri = riB[it];
                ushort4 pk = make_ushort4(f2bf(v.x * ri), f2bf(v.y * ri),
                                          f2bf(v.z * ri), f2bf(v.w * ri));
                *(ushort4*)((char*)Bs + bo) = pk;
            }
        }
        __syncthreads();
#pragma unroll
        for (int ks = 0; ks < 2; ++ks) {
            bf16x8 af[4], bfr[4];
            const int li = lane & 15;
            const int kb = ks * 64 + (lane >> 4) * 16;
#pragma unroll
            for (int m = 0; m < 4; ++m) {
                int r = wm * 64 + m * 16 + li;
                int off = (r * 128 + kb) ^ ((r & 7) << 4);
                af[m] = *(const bf16x8*)((const char*)As + off);
            }
#pragma unroll
            for (int n = 0; n < 4; ++n) {
                int r = wn * 64 + n * 16 + li;
                int off = (r * 128 + kb) ^ ((r & 7) << 4);
                bfr[n] = *(const bf16x8*)((const char*)Bs + off);
            }
#pragma unroll
            for (int m = 0; m < 4; ++m)
#pragma unroll
                for (int n = 0; n < 4; ++n)
                    acc[m][n] = __builtin_amdgcn_mfma_f32_16x16x32_bf16(
                        af[m], bfr[n], acc[m][n], 0, 0, 0);
        }
    }

    const bool diag = (bi == bj);
    const bool posT = (bcol == (brow ^ 2048));
    const int li = lane & 15;
    const int lg = lane >> 4;
    float cs[4] = {0.f, 0.f, 0.f, 0.f};
#pragma unroll
    for (int m = 0; m < 4; ++m) {
#pragma unroll
        for (int q = 0; q < 4; ++q) {
            int lr = wm * 64 + m * 16 + lg * 4 + q;
            float rsum = 0.f;
#pragma unroll
            for (int n = 0; n < 4; ++n) {
                int lc = wn * 64 + n * 16 + li;
                float v = acc[m][n][q];
                if (posT && lc == lr) { pos[brow + lr] = v; pos[bcol + lc] = v; }
                float e = (diag && lc == lr) ? 0.f : __expf(2.0f * v);
                rsum += e;
                cs[n] += e;
            }
            rsum += __shfl_xor(rsum, 1);
            rsum += __shfl_xor(rsum, 2);
            rsum += __shfl_xor(rsum, 4);
            rsum += __shfl_xor(rsum, 8);
            if (li == 0) atomicAdd(&rowsum[brow + lr], rsum);
        }
    }
    if (!diag) {
#pragma unroll
        for (int n = 0; n < 4; ++n) {
            float v = cs[n];
            v += __shfl_xor(v, 16);
            v += __shfl_xor(v, 32);
            if (lg == 0) atomicAdd(&rowsum[bcol + wn * 64 + n * 16 + li], v);
        }
    }
}

// -------- Phase 3: finalize scalar loss (also reduces kd/mse partials)
__global__ __launch_bounds__(256) void finalize(
    const float* __restrict__ rowsum, const float* __restrict__ pos,
    const float* __restrict__ kdp, const float* __restrict__ msep,
    float* __restrict__ out)
{
    const int tid = threadIdx.x;
    float c = 0.f;
    for (int i = tid; i < TWO_B; i += 256)
        c += logf(rowsum[i]) - 2.0f * pos[i];
    float kd = 0.f, ms = 0.f;
    for (int i = tid; i < 2048; i += 256) { kd += kdp[i]; ms += msep[i]; }
    c = waveReduceSum(c); kd = waveReduceSum(kd); ms = waveReduceSum(ms);
    __shared__ float sm[3][4];
    if ((tid & 63) == 0) { sm[0][tid >> 6] = c; sm[1][tid >> 6] = kd; sm[2][tid >> 6] = ms; }
    __syncthreads();
    if (tid == 0) {
        float cont = (sm[0][0] + sm[0][1] + sm[0][2] + sm[0][3]) / 4096.0f;
        float kds  = (sm[1][0] + sm[1][1] + sm[1][2] + sm[1][3]) / 2048.0f;
        float mses = (sm[2][0] + sm[2][1] + sm[2][2] + sm[2][3]) / (2048.0f * 4096.0f);
        out[0] = cont + kds + mses;
    }
}

extern "C" void kernel_launch(void* const* d_in, const int* in_sizes, int n_in,
                              void* d_out, int out_size, void* d_ws, size_t ws_size,
                              hipStream_t stream) {
    const float* et = (const float*)d_in[0];
    const float* es = (const float*)d_in[1];

    const size_t Z_BYTES = (size_t)TWO_B * 2048;  // 8 MiB fp4
    const size_t SMALL_FLOATS = 4096 * 4 + 2048 * 2;
    const bool fast = ws_size >= Z_BYTES + SMALL_FLOATS * sizeof(float);

    if (fast) {
        char* z4 = (char*)d_ws;
        float* smallf = (float*)((char*)d_ws + Z_BYTES);
        float* rowsum = smallf;
        float* pos  = smallf + 4096;
        float* qs   = smallf + 4096 * 2;
        float* rinv = smallf + 4096 * 3;
        float* kdp  = smallf + 4096 * 4;
        float* msep = smallf + 4096 * 4 + 2048;
        hipLaunchKernelGGL(row_stats, dim3(2048), dim3(256), 0, stream,
                           et, es, rinv, qs, kdp, msep, rowsum, z4);
        hipLaunchKernelGGL(cont_gemm_fp4, dim3(528), dim3(256), 0, stream, z4, qs, rowsum, pos);
        hipLaunchKernelGGL(finalize, dim3(1), dim3(256), 0, stream, rowsum, pos, kdp, msep, (float*)d_out);
    } else {
        float* ws = (float*)d_ws;
        float* rowsum = ws;
        float* pos  = ws + 4096;
        float* qs   = ws + 4096 * 2;
        float* rinv = ws + 4096 * 3;
        float* kdp  = ws + 4096 * 4;
        float* msep = ws + 4096 * 4 + 2048;
        hipMemsetAsync(rowsum, 0, 4096 * sizeof(float), stream);
        hipLaunchKernelGGL(row_stats, dim3(2048), dim3(256), 0, stream,
                           et, es, rinv, qs, kdp, msep, rowsum, (char*)nullptr);
        hipLaunchKernelGGL(cont_gemm, dim3(528), dim3(256), 0, stream, et, es, rinv, rowsum, pos);
        hipLaunchKernelGGL(finalize, dim3(1), dim3(256), 0, stream, rowsum, pos, kdp, msep, (float*)d_out);
    }
}